// Round 7
// baseline (245.522 us; speedup 1.0000x reference)
//
#include <hip/hip_runtime.h>
#include <hip/hip_bf16.h>
#include <math.h>

#define BT   8192   // B*T
#define DD   256    // D
#define EE   16     // E
#define NN   8192   // N codebook entries (C == 1)

typedef __attribute__((ext_vector_type(8))) short short8;   // bf16x8 MFMA frag
typedef __attribute__((ext_vector_type(4))) float f32x4;    // MFMA accumulator

__device__ __forceinline__ unsigned short f2bf(float x) {
  union { float f; unsigned int u; } c; c.f = x;
  unsigned int r = (c.u + 0x7FFFu + ((c.u >> 16) & 1u)) >> 16;   // RNE
  return (unsigned short)r;
}
__device__ __forceinline__ unsigned int ordf(float d) {
  union { float f; unsigned int u; } c; c.f = d;
  return ((int)c.u < 0) ? ~c.u : (c.u | 0x80000000u);
}
__device__ __forceinline__ unsigned long long shflxor64(unsigned long long v, int m) {
  unsigned int lo = (unsigned int)v, hi = (unsigned int)(v >> 32);
  lo = __shfl_xor((int)lo, m);
  hi = __shfl_xor((int)hi, m);
  return ((unsigned long long)hi << 32) | lo;
}

// ---------------- k_pre: fused Wt-transpose + embT + LN/proj/xmb ------------
// blocks [0,512):    W[d][n] fp32 -> Wt[n][d] bf16 (float4 reads, LDS-tiled)
// blocks [512,544):  emb -> embT bf16 + sqe + keys init (+done zero)
// blocks [544,800):  xmb bf16 cast, LayerNorm, projb bf16, sumexp zero
#define XT_LD 65   // float4 row stride (64 + 1 pad -> conflict-free)
__global__ __launch_bounds__(256) void k_pre(const float* __restrict__ xs,
                                             const int* __restrict__ mm,
                                             const float* __restrict__ memb,
                                             const float* __restrict__ gamma,
                                             const float* __restrict__ beta,
                                             const float* __restrict__ P,
                                             const float* __restrict__ W,
                                             const float* __restrict__ emb,
                                             unsigned short* __restrict__ xmb,
                                             unsigned short* __restrict__ projb,
                                             unsigned short* __restrict__ Wt,
                                             unsigned short* __restrict__ embT,
                                             float* __restrict__ sqe,
                                             unsigned long long* __restrict__ keys,
                                             float* __restrict__ sumexp,
                                             unsigned int* __restrict__ done) {
  __shared__ __align__(16) float xt[32 * XT_LD * 4];   // 33 KB shared scratch
  __shared__ float stats[32][2];
  int bid = blockIdx.x;
  int tid = threadIdx.x;

  if (bid < 512) {             // ---- Wt transpose: 64n x 64d tile ----
    int n0 = (bid & 127) * 64;
    int d0 = (bid >> 7) * 64;
    // float4 reads: 16 B/lane, 256 B contiguous per d-row
    #pragma unroll
    for (int pass = 0; pass < 4; pass++) {
      int idx = pass * 256 + tid;       // 1024 float4 slots = 64 d x 16 nf4
      int dd = idx >> 4, nf4 = idx & 15;
      float4 v = *(const float4*)&W[(size_t)(d0 + dd) * NN + n0 + nf4 * 4];
      xt[(nf4 * 4 + 0) * XT_LD + dd] = v.x;
      xt[(nf4 * 4 + 1) * XT_LD + dd] = v.y;
      xt[(nf4 * 4 + 2) * XT_LD + dd] = v.z;
      xt[(nf4 * 4 + 3) * XT_LD + dd] = v.w;
    }
    __syncthreads();
    #pragma unroll
    for (int pass = 0; pass < 2; pass++) {
      int g = pass * 256 + tid;
      int row = g >> 3, c8 = g & 7;
      short8 v;
      #pragma unroll
      for (int i = 0; i < 8; i++) v[i] = (short)f2bf(xt[row * XT_LD + c8 * 8 + i]);
      *(short8*)(Wt + (size_t)(n0 + row) * DD + d0 + c8 * 8) = v;
    }
    return;
  }
  if (bid < 544) {             // ---- embT + sqe + keys ----
    if (bid == 512 && tid == 0) *done = 0u;
    int n = (bid - 512) * 256 + tid;
    float e[EE];
    float sq = 0.f;
    #pragma unroll
    for (int k = 0; k < EE; k++) { e[k] = emb[k * NN + n]; sq += e[k] * e[k]; }
    short8 lo, hi;
    #pragma unroll
    for (int k = 0; k < 8; k++) { lo[k] = (short)f2bf(e[k]); hi[k] = (short)f2bf(e[k + 8]); }
    *(short8*)(embT + (size_t)n * EE)     = lo;
    *(short8*)(embT + (size_t)n * EE + 8) = hi;
    sqe[n] = sq;
    keys[n] = ~0ULL;
    return;
  }
  // ---- LN + projection + xmb ----
  int pb = bid - 544;
  int t0 = pb * 32;
  int w = tid >> 6;
  int col4 = tid & 63;
  float4 mb4 = ((const float4*)memb)[col4];

  #pragma unroll
  for (int j = 0; j < 8; j++) {
    int k = tid + j * 256;
    int row = w + j * 4;
    float4 xv = ((const float4*)xs)[(size_t)pb * 2048 + k];
    int m = mm[t0 + row];
    float4 v = m ? mb4 : xv;
    ushort2 o01 = { f2bf(v.x), f2bf(v.y) };
    ushort2 o23 = { f2bf(v.z), f2bf(v.w) };
    ((ushort2*)(xmb + (size_t)(t0 + row) * DD + col4 * 4))[0] = o01;
    ((ushort2*)(xmb + (size_t)(t0 + row) * DD + col4 * 4))[1] = o23;
    *(float4*)&xt[(row * XT_LD + col4) * 4] = xv;
  }
  __syncthreads();
  {
    int t = tid >> 3, g = tid & 7;
    float s = 0.f, s2 = 0.f;
    #pragma unroll
    for (int i = 0; i < 8; i++) {
      float4 v = *(const float4*)&xt[(t * XT_LD + g * 8 + i) * 4];
      s  += v.x + v.y + v.z + v.w;
      s2 += v.x * v.x + v.y * v.y + v.z * v.z + v.w * v.w;
    }
    #pragma unroll
    for (int m = 1; m <= 4; m <<= 1) { s += __shfl_xor(s, m); s2 += __shfl_xor(s2, m); }
    if (g == 0) {
      float mu = s * (1.0f / DD);
      float var = s2 * (1.0f / DD) - mu * mu;
      stats[t][0] = mu;
      stats[t][1] = rsqrtf(var + 1e-5f);
    }
  }
  if (tid < 32) sumexp[t0 + tid] = 0.f;
  __syncthreads();
  {
    int t = tid >> 3, e0 = (tid & 7) * 2;
    float mu = stats[t][0], rstd = stats[t][1];
    float a0 = 0.f, a1 = 0.f;
    for (int d = 0; d < DD; d += 4) {
      float4 xv = *(const float4*)&xt[(t * XT_LD + (d >> 2)) * 4];
      float xd[4] = { xv.x, xv.y, xv.z, xv.w };
      #pragma unroll
      for (int dd = 0; dd < 4; dd++) {
        float h = (xd[dd] - mu) * rstd * gamma[d + dd] + beta[d + dd];
        a0 += h * P[(d + dd) * EE + e0];
        a1 += h * P[(d + dd) * EE + e0 + 1];
      }
    }
    ushort2 o = { f2bf(a0), f2bf(a1) };
    *(ushort2*)(projb + (size_t)(t0 + t) * EE + e0) = o;
  }
}

// ------- k_argmin: MFMA dist + packed-key argmin ----------------------------
#define NS4 8
#define ASEG (NN / NS4)   // 1024 n per block
__global__ __launch_bounds__(256) void k_argmin(const unsigned short* __restrict__ projb,
                                                const unsigned short* __restrict__ embT,
                                                const float* __restrict__ sqe,
                                                unsigned long long* __restrict__ keys) {
  int tid = threadIdx.x;
  int w = tid >> 6, lane = tid & 63;
  int q = lane >> 4, c = lane & 15;
  int tw = blockIdx.x * 64 + w * 16;
  int nseg = blockIdx.y * ASEG;

  short8 a = {0, 0, 0, 0, 0, 0, 0, 0};
  if (q < 2) a = *(const short8*)(projb + (size_t)(tw + c) * EE + q * 8);

  unsigned long long bk[4];
  #pragma unroll
  for (int r = 0; r < 4; r++) bk[r] = ~0ULL;

  #pragma unroll 2
  for (int it = 0; it < ASEG / 16; it++) {
    int n = nseg + it * 16 + c;
    short8 b = {0, 0, 0, 0, 0, 0, 0, 0};
    if (q < 2) b = *(const short8*)(embT + (size_t)n * EE + q * 8);
    float sq = sqe[n];
    f32x4 acc = (f32x4){0.f, 0.f, 0.f, 0.f};
    acc = __builtin_amdgcn_mfma_f32_16x16x32_bf16(a, b, acc, 0, 0, 0);
    #pragma unroll
    for (int r = 0; r < 4; r++) {
      float dist = sq - 2.f * acc[r];
      unsigned long long key = ((unsigned long long)ordf(dist) << 32) | (unsigned int)n;
      bk[r] = key < bk[r] ? key : bk[r];
    }
  }
  #pragma unroll
  for (int r = 0; r < 4; r++) {
    #pragma unroll
    for (int m = 1; m <= 8; m <<= 1) {
      unsigned long long o = shflxor64(bk[r], m);
      bk[r] = o < bk[r] ? o : bk[r];
    }
  }
  if (c == 0) {
    #pragma unroll
    for (int r = 0; r < 4; r++)
      atomicMin(&keys[tw + q * 4 + r], bk[r]);
  }
}

// ------- k_ce7: barrier-free, A-resident, register-streamed GEMM ------------
// grid (32, 16); block 256 = 4 waves, each wave INDEPENDENT: owns 64 m-rows
// (A = 64x256 = 128 VGPRs, resident; __launch_bounds__(256,2) -> 256-VGPR
// budget). Loops its 512-n segment in 32-n chunks; B streamed from global
// (L1/L2) via 16B loads into registers -- NO LDS, NO __syncthreads in the
// hot loop, so waves slip freely and loads pipeline under MFMA.
// Fused: exp-sum accumulate + target-logit capture + (last block) final CE.
#define CE_NS 16
#define CE_SEG (NN / CE_NS)        // 512
#define CE_ITERS (CE_SEG / 32)     // 16
__global__ __launch_bounds__(256, 2) void k_ce7(const unsigned short* __restrict__ xmb,
                                                const unsigned short* __restrict__ Wt,
                                                const unsigned long long* __restrict__ keys,
                                                const int* __restrict__ padm,
                                                const int* __restrict__ mm,
                                                float* __restrict__ sumexp,
                                                float* __restrict__ ltar,
                                                unsigned int* __restrict__ done,
                                                float* __restrict__ out) {
  int tid = threadIdx.x;
  int w = tid >> 6, lane = tid & 63;
  int q = lane >> 4, c = lane & 15;
  int t0 = blockIdx.x * 256 + w * 64;        // this wave's m-base
  int nb0 = blockIdx.y * CE_SEG;

  // ---- A fragments: 64 rows x K=256, resident all kernel (128 VGPRs) ----
  short8 a[4][8];
  #pragma unroll
  for (int mi = 0; mi < 4; mi++)
    #pragma unroll
    for (int ks = 0; ks < 8; ks++)
      a[mi][ks] = *(const short8*)(xmb + (size_t)(t0 + mi * 16 + c) * DD + ks * 32 + q * 8);

  int tg[4][4];
  #pragma unroll
  for (int mi = 0; mi < 4; mi++)
    #pragma unroll
    for (int r = 0; r < 4; r++)
      tg[mi][r] = (int)(unsigned int)(keys[t0 + mi * 16 + q * 4 + r] & 0xFFFFFFFFULL);

  float rs[4][4];
  #pragma unroll
  for (int mi = 0; mi < 4; mi++)
    #pragma unroll
    for (int r = 0; r < 4; r++) rs[mi][r] = 0.f;

  for (int it = 0; it < CE_ITERS; it++) {
    int nb = nb0 + it * 32;
    f32x4 acc[4][2];
    #pragma unroll
    for (int mi = 0; mi < 4; mi++)
      #pragma unroll
      for (int ni = 0; ni < 2; ni++) acc[mi][ni] = (f32x4){0.f, 0.f, 0.f, 0.f};

    // B: 2 n-tiles x full K, straight from global into registers.
    // Per nt: 8 independent 16B loads, then 32 MFMAs (compiler pipelines).
    #pragma unroll
    for (int nt = 0; nt < 2; nt++) {
      short8 b[8];
      #pragma unroll
      for (int kc = 0; kc < 8; kc++)
        b[kc] = *(const short8*)(Wt + (size_t)(nb + nt * 16 + c) * DD + kc * 32 + q * 8);
      #pragma unroll
      for (int kc = 0; kc < 8; kc++)
        #pragma unroll
        for (int mi = 0; mi < 4; mi++)
          acc[mi][nt] = __builtin_amdgcn_mfma_f32_16x16x32_bf16(a[mi][kc], b[kc], acc[mi][nt], 0, 0, 0);
    }

    #pragma unroll
    for (int mi = 0; mi < 4; mi++)
      #pragma unroll
      for (int ni = 0; ni < 2; ni++) {
        int col = nb + ni * 16 + c;
        #pragma unroll
        for (int r = 0; r < 4; r++) {
          float v = acc[mi][ni][r];
          if (col == tg[mi][r])
            ltar[t0 + mi * 16 + q * 4 + r] = v;   // unique writer grid-wide
          rs[mi][r] += __expf(v);
        }
      }
  }

  // reduce exp-sums over the 16 column lanes, one atomic per row
  #pragma unroll
  for (int mi = 0; mi < 4; mi++)
    #pragma unroll
    for (int r = 0; r < 4; r++) {
      float s = rs[mi][r];
      s += __shfl_xor(s, 1);
      s += __shfl_xor(s, 2);
      s += __shfl_xor(s, 4);
      s += __shfl_xor(s, 8);
      if (c == 0)
        atomicAdd(&sumexp[t0 + mi * 16 + q * 4 + r], s);
    }

  // ---- last block computes the final masked mean ----
  __threadfence();            // release: ltar stores + sumexp atomics visible
  __syncthreads();
  __shared__ unsigned int lastv;
  if (tid == 0) lastv = atomicAdd(done, 1u);
  __syncthreads();
  if (lastv == 32 * CE_NS - 1) {
    __threadfence();          // acquire
    float sum = 0.f, cnt = 0.f;
    for (int t = tid; t < BT; t += 256) {
      float ce = __logf(sumexp[t]) - ltar[t];
      if (padm[t] && mm[t]) { sum += ce; cnt += 1.f; }
    }
    #pragma unroll
    for (int off = 32; off; off >>= 1) { sum += __shfl_down(sum, off); cnt += __shfl_down(cnt, off); }
    __shared__ float frs[4], frc[4];
    int wid = tid >> 6, ln = tid & 63;
    if (ln == 0) { frs[wid] = sum; frc[wid] = cnt; }
    __syncthreads();
    if (tid == 0) {
      float S = 0.f, Cn = 0.f;
      #pragma unroll
      for (int i = 0; i < 4; i++) { S += frs[i]; Cn += frc[i]; }
      out[0] = S / Cn;
    }
  }
}

extern "C" void kernel_launch(void* const* d_in, const int* in_sizes, int n_in,
                              void* d_out, int out_size, void* d_ws, size_t ws_size,
                              hipStream_t stream) {
  const float* xs    = (const float*)d_in[0];
  const int*   padm  = (const int*)d_in[1];
  const int*   mm    = (const int*)d_in[2];
  const float* gamma = (const float*)d_in[3];
  const float* beta  = (const float*)d_in[4];
  const float* P     = (const float*)d_in[5];
  const float* emb   = (const float*)d_in[6];
  const float* W     = (const float*)d_in[7];
  const float* memb  = (const float*)d_in[8];
  float* out = (float*)d_out;

  char* ws = (char*)d_ws;
  size_t off = 0;
  unsigned short* xmb   = (unsigned short*)(ws + off); off += (size_t)BT * DD * 2;  // 4 MB
  unsigned short* Wtb   = (unsigned short*)(ws + off); off += (size_t)NN * DD * 2;  // 4 MB
  unsigned short* embT  = (unsigned short*)(ws + off); off += (size_t)NN * EE * 2;  // 256 KB
  unsigned short* projb = (unsigned short*)(ws + off); off += (size_t)BT * EE * 2;  // 256 KB
  float* sqe            = (float*)(ws + off);          off += (size_t)NN * 4;       // 32 KB
  unsigned long long* keys = (unsigned long long*)(ws + off); off += (size_t)BT * 8;// 64 KB
  float* sumexp         = (float*)(ws + off);          off += (size_t)BT * 4;       // 32 KB
  float* ltar           = (float*)(ws + off);          off += (size_t)BT * 4;       // 32 KB
  unsigned int* done    = (unsigned int*)(ws + off);   off += 64;

  k_pre   <<<800, 256, 0, stream>>>(xs, mm, memb, gamma, beta, P, W, emb,
                                    xmb, projb, Wtb, embT, sqe, keys, sumexp, done);
  k_argmin<<<dim3(BT / 64, NS4), 256, 0, stream>>>(projb, embT, sqe, keys);
  k_ce7   <<<dim3(32, CE_NS), 256, 0, stream>>>(xmb, Wtb, keys, padm, mm,
                                                sumexp, ltar, done, out);
}

// Round 8
// 219.189 us; speedup vs baseline: 1.1201x; 1.1201x over previous
//
#include <hip/hip_runtime.h>
#include <hip/hip_bf16.h>
#include <math.h>

#define BT   8192   // B*T
#define DD   256    // D
#define EE   16     // E
#define NN   8192   // N codebook entries (C == 1)

typedef __attribute__((ext_vector_type(8))) short short8;   // bf16x8 MFMA frag
typedef __attribute__((ext_vector_type(4))) float f32x4;    // MFMA accumulator
typedef __attribute__((ext_vector_type(2))) long long2v;    // 16B = two fp8 K-frags

__device__ __forceinline__ unsigned short f2bf(float x) {
  union { float f; unsigned int u; } c; c.f = x;
  unsigned int r = (c.u + 0x7FFFu + ((c.u >> 16) & 1u)) >> 16;   // RNE
  return (unsigned short)r;
}
__device__ __forceinline__ unsigned int ordf(float d) {
  union { float f; unsigned int u; } c; c.f = d;
  return ((int)c.u < 0) ? ~c.u : (c.u | 0x80000000u);
}
__device__ __forceinline__ unsigned long long shflxor64(unsigned long long v, int m) {
  unsigned int lo = (unsigned int)v, hi = (unsigned int)(v >> 32);
  lo = __shfl_xor((int)lo, m);
  hi = __shfl_xor((int)hi, m);
  return ((unsigned long long)hi << 32) | lo;
}
__device__ __forceinline__ void gload_lds16(const void* g, void* l) {
  __builtin_amdgcn_global_load_lds((const __attribute__((address_space(1))) void*)g,
                                   (__attribute__((address_space(3))) void*)l, 16, 0, 0);
}
// pack 4 floats -> 4 OCP e4m3 bytes (HW RNE)
__device__ __forceinline__ unsigned int pk_fp8x4(float a, float b, float c, float d) {
  int p = __builtin_amdgcn_cvt_pk_fp8_f32(a, b, 0, false);
  p = __builtin_amdgcn_cvt_pk_fp8_f32(c, d, p, true);
  return (unsigned int)p;
}

// ---------------- k_pre: fused Wq-transpose + embT + LN/proj/xq -------------
// fp8 arrays use the q-major permuted byte order within each 256-B row:
//   d' = q*64 + kc*8 + i   for source d = kc*32 + q*8 + i  (kc in [0,8))
// (A and B permuted identically -> MFMA result unchanged.)
// blocks [0,512):    W[d][n] fp32 -> Wq[n][d'] fp8
// blocks [512,544):  emb -> embT bf16 + sqe + keys init (+done zero)
// blocks [544,800):  xq fp8 (masked), LayerNorm, projb bf16, sumexp zero
#define XT_LD 65   // float4 row stride (64 + 1 pad -> conflict-free)
__global__ __launch_bounds__(256) void k_pre(const float* __restrict__ xs,
                                             const int* __restrict__ mm,
                                             const float* __restrict__ memb,
                                             const float* __restrict__ gamma,
                                             const float* __restrict__ beta,
                                             const float* __restrict__ P,
                                             const float* __restrict__ W,
                                             const float* __restrict__ emb,
                                             unsigned char* __restrict__ xq,
                                             unsigned short* __restrict__ projb,
                                             unsigned char* __restrict__ Wq,
                                             unsigned short* __restrict__ embT,
                                             float* __restrict__ sqe,
                                             unsigned long long* __restrict__ keys,
                                             float* __restrict__ sumexp,
                                             unsigned int* __restrict__ done) {
  __shared__ __align__(16) float xt[32 * XT_LD * 4];   // 33 KB shared scratch
  __shared__ float stats[32][2];
  int bid = blockIdx.x;
  int tid = threadIdx.x;

  if (bid < 512) {             // ---- Wq transpose: 64n x 64d tile ----
    int n0 = (bid & 127) * 64;
    int d0 = (bid >> 7) * 64;
    #pragma unroll
    for (int pass = 0; pass < 4; pass++) {
      int idx = pass * 256 + tid;       // 1024 float4 slots = 64 d x 16 nf4
      int dd = idx >> 4, nf4 = idx & 15;
      float4 v = *(const float4*)&W[(size_t)(d0 + dd) * NN + n0 + nf4 * 4];
      xt[(nf4 * 4 + 0) * XT_LD + dd] = v.x;
      xt[(nf4 * 4 + 1) * XT_LD + dd] = v.y;
      xt[(nf4 * 4 + 2) * XT_LD + dd] = v.z;
      xt[(nf4 * 4 + 3) * XT_LD + dd] = v.w;
    }
    __syncthreads();
    #pragma unroll
    for (int pass = 0; pass < 2; pass++) {
      int g = pass * 256 + tid;
      int row = g >> 3, c8 = g & 7;      // d = d0 + c8*8 + i
      float v[8];
      #pragma unroll
      for (int i = 0; i < 8; i++) v[i] = xt[row * XT_LD + c8 * 8 + i];
      uint2 o;
      o.x = pk_fp8x4(v[0], v[1], v[2], v[3]);
      o.y = pk_fp8x4(v[4], v[5], v[6], v[7]);
      // permuted dest: q = c8&3, kc = (d0>>5) + (c8>>2)
      int dp = (c8 & 3) * 64 + ((d0 >> 5) + (c8 >> 2)) * 8;
      *(uint2*)&Wq[(size_t)(n0 + row) * DD + dp] = o;
    }
    return;
  }
  if (bid < 544) {             // ---- embT + sqe + keys ----
    if (bid == 512 && tid == 0) *done = 0u;
    int n = (bid - 512) * 256 + tid;
    float e[EE];
    float sq = 0.f;
    #pragma unroll
    for (int k = 0; k < EE; k++) { e[k] = emb[k * NN + n]; sq += e[k] * e[k]; }
    short8 lo, hi;
    #pragma unroll
    for (int k = 0; k < 8; k++) { lo[k] = (short)f2bf(e[k]); hi[k] = (short)f2bf(e[k + 8]); }
    *(short8*)(embT + (size_t)n * EE)     = lo;
    *(short8*)(embT + (size_t)n * EE + 8) = hi;
    sqe[n] = sq;
    keys[n] = ~0ULL;
    return;
  }
  // ---- LN + projection + xq ----
  int pb = bid - 544;
  int t0 = pb * 32;
  int w = tid >> 6;
  int col4 = tid & 63;
  float4 mb4 = ((const float4*)memb)[col4];
  // permuted dest for d = col4*4: q=(col4>>1)&3, kc=col4>>3, i0=(col4&1)*4
  int dpx = ((col4 >> 1) & 3) * 64 + (col4 >> 3) * 8 + (col4 & 1) * 4;

  #pragma unroll
  for (int j = 0; j < 8; j++) {
    int k = tid + j * 256;
    int row = w + j * 4;
    float4 xv = ((const float4*)xs)[(size_t)pb * 2048 + k];
    int m = mm[t0 + row];
    float4 v = m ? mb4 : xv;
    *(unsigned int*)&xq[(size_t)(t0 + row) * DD + dpx] = pk_fp8x4(v.x, v.y, v.z, v.w);
    *(float4*)&xt[(row * XT_LD + col4) * 4] = xv;
  }
  __syncthreads();
  {
    int t = tid >> 3, g = tid & 7;
    float s = 0.f, s2 = 0.f;
    #pragma unroll
    for (int i = 0; i < 8; i++) {
      float4 v = *(const float4*)&xt[(t * XT_LD + g * 8 + i) * 4];
      s  += v.x + v.y + v.z + v.w;
      s2 += v.x * v.x + v.y * v.y + v.z * v.z + v.w * v.w;
    }
    #pragma unroll
    for (int m = 1; m <= 4; m <<= 1) { s += __shfl_xor(s, m); s2 += __shfl_xor(s2, m); }
    if (g == 0) {
      float mu = s * (1.0f / DD);
      float var = s2 * (1.0f / DD) - mu * mu;
      stats[t][0] = mu;
      stats[t][1] = rsqrtf(var + 1e-5f);
    }
  }
  if (tid < 32) sumexp[t0 + tid] = 0.f;
  __syncthreads();
  {
    int t = tid >> 3, e0 = (tid & 7) * 2;
    float mu = stats[t][0], rstd = stats[t][1];
    float a0 = 0.f, a1 = 0.f;
    for (int d = 0; d < DD; d += 4) {
      float4 xv = *(const float4*)&xt[(t * XT_LD + (d >> 2)) * 4];
      float xd[4] = { xv.x, xv.y, xv.z, xv.w };
      #pragma unroll
      for (int dd = 0; dd < 4; dd++) {
        float h = (xd[dd] - mu) * rstd * gamma[d + dd] + beta[d + dd];
        a0 += h * P[(d + dd) * EE + e0];
        a1 += h * P[(d + dd) * EE + e0 + 1];
      }
    }
    ushort2 o = { f2bf(a0), f2bf(a1) };
    *(ushort2*)(projb + (size_t)(t0 + t) * EE + e0) = o;
  }
}

// ------- k_argmin: MFMA dist + packed-key argmin (bf16, unchanged) ----------
#define NS4 8
#define ASEG (NN / NS4)   // 1024 n per block
__global__ __launch_bounds__(256) void k_argmin(const unsigned short* __restrict__ projb,
                                                const unsigned short* __restrict__ embT,
                                                const float* __restrict__ sqe,
                                                unsigned long long* __restrict__ keys) {
  int tid = threadIdx.x;
  int w = tid >> 6, lane = tid & 63;
  int q = lane >> 4, c = lane & 15;
  int tw = blockIdx.x * 64 + w * 16;
  int nseg = blockIdx.y * ASEG;

  short8 a = {0, 0, 0, 0, 0, 0, 0, 0};
  if (q < 2) a = *(const short8*)(projb + (size_t)(tw + c) * EE + q * 8);

  unsigned long long bk[4];
  #pragma unroll
  for (int r = 0; r < 4; r++) bk[r] = ~0ULL;

  #pragma unroll 2
  for (int it = 0; it < ASEG / 16; it++) {
    int n = nseg + it * 16 + c;
    short8 b = {0, 0, 0, 0, 0, 0, 0, 0};
    if (q < 2) b = *(const short8*)(embT + (size_t)n * EE + q * 8);
    float sq = sqe[n];
    f32x4 acc = (f32x4){0.f, 0.f, 0.f, 0.f};
    acc = __builtin_amdgcn_mfma_f32_16x16x32_bf16(a, b, acc, 0, 0, 0);
    #pragma unroll
    for (int r = 0; r < 4; r++) {
      float dist = sq - 2.f * acc[r];
      unsigned long long key = ((unsigned long long)ordf(dist) << 32) | (unsigned int)n;
      bk[r] = key < bk[r] ? key : bk[r];
    }
  }
  #pragma unroll
  for (int r = 0; r < 4; r++) {
    #pragma unroll
    for (int m = 1; m <= 8; m <<= 1) {
      unsigned long long o = shflxor64(bk[r], m);
      bk[r] = o < bk[r] ? o : bk[r];
    }
  }
  if (c == 0) {
    #pragma unroll
    for (int r = 0; r < 4; r++)
      atomicMin(&keys[tw + q * 4 + r], bk[r]);
  }
}

// ------- k_ce8: fp8 GEMM, A-tile resident in LDS (full K), B streamed -------
// grid (64, 8); block 512 = 8 waves (4m x 2n); block = 128 m-rows x 1024 n.
// A (128x256 fp8 = 32 KB) staged ONCE; B in 16 chunks of 64n x 256K (16 KB),
// double-buffered. 512 blocks = exactly 2/CU (one round, no tail).
// Per-row xor-swizzle of 16-B slots applied on the GLOBAL source side of
// global_load_lds (LDS dest stays lane-linear); reads use ss = (q*4+j)^c ->
// conflict-free per 16-lane phase. One b128 read = two K=32 fp8 fragments.
#define CE8_NG 8
#define CE8_CH 16
__global__ __launch_bounds__(512, 4) void k_ce8(const unsigned char* __restrict__ xq,
                                                const unsigned char* __restrict__ Wq,
                                                const unsigned long long* __restrict__ keys,
                                                const int* __restrict__ padm,
                                                const int* __restrict__ mm,
                                                float* __restrict__ sumexp,
                                                float* __restrict__ ltar,
                                                unsigned int* __restrict__ done,
                                                float* __restrict__ out) {
  __shared__ __align__(16) unsigned char ldsA[128 * 256];      // 32 KB
  __shared__ __align__(16) unsigned char ldsB[2][64 * 256];    // 32 KB
  int tid = threadIdx.x;
  int w = tid >> 6, lane = tid & 63;
  int q = lane >> 4, c = lane & 15;
  int wm = w >> 1, wn = w & 1;
  int t0 = blockIdx.x * 128;
  int ng0 = blockIdx.y * (NN / CE8_NG);   // 1024-wide n group

  // stage A (once) + B chunk 0
  #pragma unroll
  for (int p = 0; p < 4; p++) {
    int g = p * 512 + tid;
    int row = g >> 4, ss = g & 15;
    gload_lds16(xq + (size_t)(t0 + row) * DD + ((ss ^ (row & 15)) * 16), ldsA + g * 16);
  }
  #pragma unroll
  for (int p = 0; p < 2; p++) {
    int g = p * 512 + tid;
    int row = g >> 4, ss = g & 15;
    gload_lds16(Wq + (size_t)(ng0 + row) * DD + ((ss ^ (row & 15)) * 16), ldsB[0] + g * 16);
  }

  int tg[2][4];
  float rs[2][4];
  #pragma unroll
  for (int mi = 0; mi < 2; mi++)
    #pragma unroll
    for (int r = 0; r < 4; r++) {
      tg[mi][r] = (int)(unsigned int)(keys[t0 + wm * 32 + mi * 16 + q * 4 + r] & 0xFFFFFFFFULL);
      rs[mi][r] = 0.f;
    }

  __syncthreads();   // A + chunk0 staged (compiler drains vmcnt before barrier)

  for (int ch = 0; ch < CE8_CH; ch++) {
    if (ch + 1 < CE8_CH) {         // prefetch next B chunk into other buffer
      int nb = ng0 + (ch + 1) * 64;
      #pragma unroll
      for (int p = 0; p < 2; p++) {
        int g = p * 512 + tid;
        int row = g >> 4, ss = g & 15;
        gload_lds16(Wq + (size_t)(nb + row) * DD + ((ss ^ (row & 15)) * 16),
                    ldsB[(ch + 1) & 1] + g * 16);
      }
    }
    const unsigned char* bp = ldsB[ch & 1];

    f32x4 acc[2][2];
    #pragma unroll
    for (int mi = 0; mi < 2; mi++)
      #pragma unroll
      for (int ni = 0; ni < 2; ni++) acc[mi][ni] = (f32x4){0.f, 0.f, 0.f, 0.f};

    #pragma unroll
    for (int j = 0; j < 4; j++) {
      int ssr = ((q * 4 + j) ^ c) * 16;
      long2v av[2], bv[2];
      #pragma unroll
      for (int mi = 0; mi < 2; mi++)
        av[mi] = *(const long2v*)(ldsA + (wm * 32 + mi * 16 + c) * 256 + ssr);
      #pragma unroll
      for (int ni = 0; ni < 2; ni++)
        bv[ni] = *(const long2v*)(bp + (wn * 32 + ni * 16 + c) * 256 + ssr);
      #pragma unroll
      for (int mi = 0; mi < 2; mi++)
        #pragma unroll
        for (int ni = 0; ni < 2; ni++) {
          acc[mi][ni] = __builtin_amdgcn_mfma_f32_16x16x32_fp8_fp8(av[mi][0], bv[ni][0], acc[mi][ni], 0, 0, 0);
          acc[mi][ni] = __builtin_amdgcn_mfma_f32_16x16x32_fp8_fp8(av[mi][1], bv[ni][1], acc[mi][ni], 0, 0, 0);
        }
    }

    int nbase = ng0 + ch * 64 + wn * 32;
    #pragma unroll
    for (int mi = 0; mi < 2; mi++)
      #pragma unroll
      for (int ni = 0; ni < 2; ni++) {
        int col = nbase + ni * 16 + c;
        #pragma unroll
        for (int r = 0; r < 4; r++) {
          float v = acc[mi][ni][r];
          if (col == tg[mi][r])
            ltar[t0 + wm * 32 + mi * 16 + q * 4 + r] = v;   // unique writer grid-wide
          rs[mi][r] += __expf(v);
        }
      }
    __syncthreads();   // next chunk staged; safe to overwrite other buffer
  }

  // reduce exp-sums over the 16 column lanes, one atomic per row
  #pragma unroll
  for (int mi = 0; mi < 2; mi++)
    #pragma unroll
    for (int r = 0; r < 4; r++) {
      float s = rs[mi][r];
      s += __shfl_xor(s, 1);
      s += __shfl_xor(s, 2);
      s += __shfl_xor(s, 4);
      s += __shfl_xor(s, 8);
      if (c == 0)
        atomicAdd(&sumexp[t0 + wm * 32 + mi * 16 + q * 4 + r], s);
    }

  // ---- last block computes the final masked mean ----
  __threadfence();            // release: ltar stores + sumexp atomics visible
  __syncthreads();
  __shared__ unsigned int lastv;
  if (tid == 0) lastv = atomicAdd(done, 1u);
  __syncthreads();
  if (lastv == 64 * CE8_NG - 1) {
    __threadfence();          // acquire
    float sum = 0.f, cnt = 0.f;
    for (int t = tid; t < BT; t += 512) {
      float ce = __logf(sumexp[t]) - ltar[t];
      if (padm[t] && mm[t]) { sum += ce; cnt += 1.f; }
    }
    #pragma unroll
    for (int off = 32; off; off >>= 1) { sum += __shfl_down(sum, off); cnt += __shfl_down(cnt, off); }
    __shared__ float frs[8], frc[8];
    int wid = tid >> 6, ln = tid & 63;
    if (ln == 0) { frs[wid] = sum; frc[wid] = cnt; }
    __syncthreads();
    if (tid == 0) {
      float S = 0.f, Cn = 0.f;
      #pragma unroll
      for (int i = 0; i < 8; i++) { S += frs[i]; Cn += frc[i]; }
      out[0] = S / Cn;
    }
  }
}

extern "C" void kernel_launch(void* const* d_in, const int* in_sizes, int n_in,
                              void* d_out, int out_size, void* d_ws, size_t ws_size,
                              hipStream_t stream) {
  const float* xs    = (const float*)d_in[0];
  const int*   padm  = (const int*)d_in[1];
  const int*   mm    = (const int*)d_in[2];
  const float* gamma = (const float*)d_in[3];
  const float* beta  = (const float*)d_in[4];
  const float* P     = (const float*)d_in[5];
  const float* emb   = (const float*)d_in[6];
  const float* W     = (const float*)d_in[7];
  const float* memb  = (const float*)d_in[8];
  float* out = (float*)d_out;

  char* ws = (char*)d_ws;
  size_t off = 0;
  unsigned char* xq     = (unsigned char*)(ws + off);  off += (size_t)BT * DD;      // 2 MB
  unsigned char* Wq     = (unsigned char*)(ws + off);  off += (size_t)NN * DD;      // 2 MB
  unsigned short* embT  = (unsigned short*)(ws + off); off += (size_t)NN * EE * 2;  // 256 KB
  unsigned short* projb = (unsigned short*)(ws + off); off += (size_t)BT * EE * 2;  // 256 KB
  float* sqe            = (float*)(ws + off);          off += (size_t)NN * 4;       // 32 KB
  unsigned long long* keys = (unsigned long long*)(ws + off); off += (size_t)BT * 8;// 64 KB
  float* sumexp         = (float*)(ws + off);          off += (size_t)BT * 4;       // 32 KB
  float* ltar           = (float*)(ws + off);          off += (size_t)BT * 4;       // 32 KB
  unsigned int* done    = (unsigned int*)(ws + off);   off += 64;

  k_pre   <<<800, 256, 0, stream>>>(xs, mm, memb, gamma, beta, P, W, emb,
                                    xq, projb, Wq, embT, sqe, keys, sumexp, done);
  k_argmin<<<dim3(BT / 64, NS4), 256, 0, stream>>>(projb, embT, sqe, keys);
  k_ce8   <<<dim3(BT / 128, CE8_NG), 512, 0, stream>>>(xq, Wq, keys, padm, mm,
                                                       sumexp, ltar, done, out);
}